// Round 8
// baseline (244.649 us; speedup 1.0000x reference)
//
#include <hip/hip_runtime.h>
#include <hip/hip_bf16.h>

#define N_SUP 16384
#define M_Q   4096
#define TV    27
#define CIN   41
#define CH1   864
#define CH2   128
#define CAP   1024
#define NB    12          // bins per xy axis (width 50/12 = 4.17 >= 4)

// kC tiling: BM=8 rows, BN=128 cols, BK=32, 2x2 per thread, grid 512 -> 2 blocks/CU
#define CBM 8
#define CBK 32

// grid offset value for axis-index 0/1/2 : linspace(-R+R/NV, R-R/NV, 3) = {-1.3333334, 0, +1.3333334}
__device__ __forceinline__ float gsel(int i){
  const float GOFF = (float)(-2.0 + 2.0 / 3.0);   // -1.3333334f (matches f32 linspace endpoint)
  return (i == 0) ? GOFF : ((i == 2) ? -GOFF : 0.0f);
}

__device__ __forceinline__ int binOf(float x){
  int b = (int)(x * (float)(NB / 50.0));
  return (b < 0) ? 0 : ((b > NB - 1) ? NB - 1 : b);
}

// branchless 3-deep insert of u64 key (keeps k0 <= k1 <= k2)
__device__ __forceinline__ void insK(unsigned long long key,
                                     unsigned long long& k0,
                                     unsigned long long& k1,
                                     unsigned long long& k2){
  bool b0 = key < k0, b1 = key < k1, b2 = key < k2;
  k2 = b1 ? k1 : (b2 ? key : k2);
  k1 = b0 ? k0 : (b1 ? key : k1);
  k0 = b0 ? key : k0;
}

// ---------------- Kernel WT: transpose w1 and w2 ----------------
__global__ void kWT(const float* __restrict__ w1, float* __restrict__ w1T,
                    const float* __restrict__ w2, float* __restrict__ w2T)
{
  int idx = blockIdx.x * 256 + threadIdx.x;
  if (idx < CIN * CH1) {
    int k = idx / CH1, t = idx % CH1;
    w1T[idx] = w1[(size_t)t * CIN + k];
  }
  int j = idx - CIN * CH1;
  if (j >= 0 && j < CH1 * CH2) {
    int k = j / CH2, c = j % CH2;
    w2T[j] = w2[(size_t)c * CH1 + k];
  }
}

// ---------------- binning: count / scan / scatter ----------------
__global__ void kCount(const float* __restrict__ sup_xyz, int* __restrict__ counts)
{
  int i = blockIdx.x * 256 + threadIdx.x;
  if (i < N_SUP) {
    float x = sup_xyz[3*i], y = sup_xyz[3*i+1];
    atomicAdd(&counts[binOf(x) * NB + binOf(y)], 1);
  }
}

__global__ void kScan(const int* __restrict__ counts, int* __restrict__ starts, int* __restrict__ cursor)
{
  __shared__ int sc[NB*NB];
  int t = threadIdx.x;
  if (t < NB*NB) sc[t] = counts[t];
  __syncthreads();
  if (t == 0) {
    int acc = 0;
    for (int b = 0; b < NB*NB; b++) { int c = sc[b]; sc[b] = acc; acc += c; }
  }
  __syncthreads();
  if (t < NB*NB) { starts[t] = sc[t]; cursor[t] = sc[t]; }
  if (t == NB*NB) starts[NB*NB] = N_SUP;
}

__global__ void kScatter(const float* __restrict__ sup_xyz, int* __restrict__ cursor,
                         float* __restrict__ xs, float* __restrict__ ys,
                         float* __restrict__ zs, int* __restrict__ sid)
{
  int i = blockIdx.x * 256 + threadIdx.x;
  if (i < N_SUP) {
    float x = sup_xyz[3*i], y = sup_xyz[3*i+1], z = sup_xyz[3*i+2];
    int b = binOf(x) * NB + binOf(y);
    int p = atomicAdd(&cursor[b], 1);
    xs[p] = x; ys[p] = y; zs[p] = z; sid[p] = i;
  }
}

// ---------------- Kernel A12: bin-pruned cube filter + dq-sorted pruned 3NN ----------------
__global__ __launch_bounds__(256) void kA12(const float* __restrict__ xs,
                                            const float* __restrict__ ys,
                                            const float* __restrict__ zs,
                                            const int*   __restrict__ sid,
                                            const int*   __restrict__ starts,
                                            const float* __restrict__ new_xyz,
                                            const float* __restrict__ sup_xyz,
                                            float* __restrict__ nnW,
                                            int*   __restrict__ nnGI,
                                            float* __restrict__ nnLX)
{
  __shared__ float4 cxyz[CAP];
  __shared__ unsigned long long skeys[CAP];
  __shared__ unsigned long long sk[TV][8][3];
  __shared__ int s_cnt;

  const int m   = blockIdx.x;
  const int tid = threadIdx.x;
  if (tid == 0) s_cnt = 0;
  __syncthreads();

  const float qx = new_xyz[m*3+0];
  const float qy = new_xyz[m*3+1];
  const float qz = new_xyz[m*3+2];

  // ---- phase 1: cube filter over <=3x3 bins (z-test vacuous) ----
  const int bx0 = binOf(qx - 4.0f), bx1 = binOf(qx + 4.0f);
  const int by0 = binOf(qy - 4.0f), by1 = binOf(qy + 4.0f);
  for (int bx = bx0; bx <= bx1; bx++) {
    const int beg = starts[bx * NB + by0];
    const int end = starts[bx * NB + by1 + 1];
    for (int i = beg + tid; i < end; i += 256) {
      float x = xs[i], y = ys[i];
      if (fabsf(__fsub_rn(x, qx)) <= 4.0f && fabsf(__fsub_rn(y, qy)) <= 4.0f) {
        int p = atomicAdd(&s_cnt, 1);
        if (p < CAP) cxyz[p] = make_float4(x, y, zs[i], __uint_as_float((unsigned)sid[i]));
      }
    }
  }
  __syncthreads();
  const int cnt = (s_cnt < CAP) ? s_cnt : CAP;

  // ---- phase 1.5: sort candidates by distance to q (keys: [dq_bits | slot]) ----
  unsigned n = 2;
  while (n < (unsigned)cnt) n <<= 1;
  for (unsigned i = tid; i < n; i += 256) {
    if (i < (unsigned)cnt) {
      float4 f4 = cxyz[i];
      float dx = qx - f4.x, dy = qy - f4.y, dz = qz - f4.z;   // our bound metric: any rounding ok
      float dq = sqrtf(dx*dx + dy*dy + dz*dz);
      skeys[i] = ((unsigned long long)__float_as_uint(dq) << 32) | (unsigned long long)i;
    } else {
      skeys[i] = ~0ull;
    }
  }
  for (unsigned bk = 2; bk <= n; bk <<= 1) {
    for (unsigned bj = bk >> 1; bj > 0; bj >>= 1) {
      __syncthreads();
      for (unsigned i = tid; i < n; i += 256) {
        unsigned l = i ^ bj;
        if (l > i) {
          unsigned long long a = skeys[i], b = skeys[l];
          bool up = ((i & bk) == 0);
          if ((a > b) == up) { skeys[i] = b; skeys[l] = a; }
        }
      }
    }
  }
  __syncthreads();

  // ---- phase 2a: strided scan in sorted order with provable early break ----
  // break when (dq - 2.30951)^2 > k2.d2 * (1+1e-6): candidate provably cannot
  // enter this thread's top-3 (|g-q| <= sqrt(3)*1.3333334 = 2.3094013 < 2.30951)
  const int v = tid >> 3, j = tid & 7;
  if (v < TV) {
    const float gx = qx + gsel(v / 9);
    const float gy = qy + gsel((v / 3) % 3);
    const float gz = qz + gsel(v % 3);
    unsigned long long k0 = ~0ull, k1 = ~0ull, k2 = ~0ull;
    for (int c = j; c < cnt; c += 8) {
      unsigned long long sk_ = skeys[c];
      float dqf = __uint_as_float((unsigned)(sk_ >> 32));
      float t = dqf - 2.30951f;
      float k2d = __uint_as_float((unsigned)(k2 >> 32));   // NaN while k2 is sentinel -> no break
      if (t > 0.0f && t * t > k2d * 1.000001f) break;
      int slot = (int)(sk_ & 0x3FFull);
      float4 f4 = cxyz[slot];
      float dx = __fsub_rn(gx, f4.x);
      float dy = __fsub_rn(gy, f4.y);
      float dz = __fsub_rn(gz, f4.z);
      // forbid FMA contraction: must match numpy f32 (mul, mul, add, mul, add)
      float dd = __fadd_rn(__fadd_rn(__fmul_rn(dx,dx), __fmul_rn(dy,dy)), __fmul_rn(dz,dz));
      unsigned long long key = ((unsigned long long)__float_as_uint(dd) << 32)
                             | (unsigned long long)__float_as_uint(f4.w);   // low = sid (tie-break)
      insK(key, k0, k1, k2);
    }
    sk[v][j][0] = k0; sk[v][j][1] = k1; sk[v][j][2] = k2;
  }
  __syncthreads();

  // ---- phase 2b: merge 8x3 keys per voxel + emit (threads 0..26) ----
  if (tid < TV) {
    const int vv = tid;
    const float gx = qx + gsel(vv / 9);
    const float gy = qy + gsel((vv / 3) % 3);
    const float gz = qz + gsel(vv % 3);
    unsigned long long k0 = ~0ull, k1 = ~0ull, k2 = ~0ull;
    #pragma unroll
    for (int jj = 0; jj < 8; jj++) {
      insK(sk[vv][jj][0], k0, k1, k2);
      insK(sk[vv][jj][1], k0, k1, k2);
      insK(sk[vv][jj][2], k0, k1, k2);
    }
    const int base = m * TV + vv;
    if (cnt > 0) {
      unsigned long long ks[3] = {k0, k1, k2};
      float d[3]; int gi[3]; bool ok[3];
      #pragma unroll
      for (int r = 0; r < 3; r++) {
        unsigned db = (unsigned)(ks[r] >> 32);
        ok[r] = (db != 0xFFFFFFFFu);
        d[r]  = ok[r] ? __uint_as_float(db) : 1e10f;
        gi[r] = ok[r] ? (int)(unsigned)(ks[r] & 0xFFFFFFFFull) : 0;
      }
      float r0 = 1.0f / (d[0] + 1e-8f);
      float r1 = 1.0f / (d[1] + 1e-8f);
      float r2 = 1.0f / (d[2] + 1e-8f);
      float den = fmaxf(r0 + r1 + r2, 1e-8f);
      nnW[base*3+0] = r0 / den; nnW[base*3+1] = r1 / den; nnW[base*3+2] = r2 / den;
      nnGI[base*3+0] = gi[0]; nnGI[base*3+1] = gi[1]; nnGI[base*3+2] = gi[2];
      #pragma unroll
      for (int r = 0; r < 3; r++) {
        if (ok[r]) {
          nnLX[base*9 + r*3 + 0] = gx - sup_xyz[gi[r]*3 + 0];
          nnLX[base*9 + r*3 + 1] = gy - sup_xyz[gi[r]*3 + 1];
          nnLX[base*9 + r*3 + 2] = gz - sup_xyz[gi[r]*3 + 2];
        } else {
          nnLX[base*9 + r*3 + 0] = 0.0f;
          nnLX[base*9 + r*3 + 1] = 0.0f;
          nnLX[base*9 + r*3 + 2] = 0.0f;
        }
      }
    } else {
      #pragma unroll
      for (int r = 0; r < 3; r++) {
        nnW[base*3+r] = 0.0f; nnGI[base*3+r] = 0;
        nnLX[base*9+r*3+0] = 0.0f; nnLX[base*9+r*3+1] = 0.0f; nnLX[base*9+r*3+2] = 0.0f;
      }
    }
  }
}

// ---------------- Kernel A3: interp features + grouped conv1, 8 queries per block ----------------
__global__ __launch_bounds__(256) void kA3(const float* __restrict__ sup_feat,
                                           const float* __restrict__ nnW,
                                           const int*   __restrict__ nnGI,
                                           const float* __restrict__ nnLX,
                                           const float* __restrict__ w1T,
                                           float* __restrict__ y1)
{
  __shared__ float s_feats[8][TV][CIN];
  __shared__ float s_w[8][TV][3];
  __shared__ int   s_gi[8][TV][3];

  const int m0  = blockIdx.x * 8;
  const int tid = threadIdx.x;

  for (int t = tid; t < 8*TV*3; t += 256) {
    int q = t / (TV*3), rem = t % (TV*3);
    s_w[q][rem/3][rem%3]  = nnW[m0*TV*3 + t];
    s_gi[q][rem/3][rem%3] = nnGI[m0*TV*3 + t];
  }
  for (int t = tid; t < 8*TV*9; t += 256) {
    int q = t / (TV*9), rem = t % (TV*9);
    s_feats[q][rem/9][32 + rem%9] = nnLX[m0*TV*9 + t];
  }
  __syncthreads();

  for (int t = tid; t < 8*TV*32; t += 256) {
    const int q = t / (TV*32), rem = t % (TV*32);
    const int v = rem >> 5, ch = rem & 31;
    s_feats[q][v][ch] = s_w[q][v][0] * sup_feat[s_gi[q][v][0]*32 + ch]
                      + s_w[q][v][1] * sup_feat[s_gi[q][v][1]*32 + ch]
                      + s_w[q][v][2] * sup_feat[s_gi[q][v][2]*32 + ch];
  }
  __syncthreads();

  for (int t = tid; t < CH1; t += 256) {
    const int v = t >> 5;
    float acc[8];
    #pragma unroll
    for (int q = 0; q < 8; q++) acc[q] = 0.0f;
    for (int k = 0; k < CIN; k++) {
      float w = w1T[k * CH1 + t];
      #pragma unroll
      for (int q = 0; q < 8; q++) acc[q] += s_feats[q][v][k] * w;
    }
    #pragma unroll
    for (int q = 0; q < 8; q++) y1[(size_t)(m0 + q) * CH1 + t] = acc[q];
  }
}

// ---------------- Kernel B: BN1 stats ----------------
__global__ void kB(const float* __restrict__ y1, float* __restrict__ stats1)
{
  const int c  = threadIdx.x;        // 864 threads
  const int m0 = blockIdx.x * 64;    // 64 blocks
  float s = 0.0f, ss = 0.0f;
  for (int r = 0; r < 64; r++) {
    float v = y1[(size_t)(m0 + r) * CH1 + c];
    s += v; ss += v * v;
  }
  atomicAdd(&stats1[c],       s);
  atomicAdd(&stats1[CH1 + c], ss);
}

// ---------------- Kernel C: BN1-fused GEMM, BM=8 x BN=128, 2x2/thread, grid 512 ----------------
__global__ __launch_bounds__(256) void kC(const float* __restrict__ y1,
                                          const float* __restrict__ stats1,
                                          const float* __restrict__ g1,
                                          const float* __restrict__ b1,
                                          const float* __restrict__ w2T,
                                          float* __restrict__ z,
                                          float* __restrict__ stats2)   // [8][256]
{
  __shared__ float As[CBK][10];        // stride 10: conflict-free, 8B-aligned rows
  __shared__ float Bs[CBK][CH2];       // 16 KB
  __shared__ float scs[CH1], shs[CH1]; // 6.9 KB
  __shared__ float st_s[2][CH2];       // 1 KB

  const int tid = threadIdx.x;
  const int m0  = blockIdx.x * CBM;

  for (int c = tid; c < CH1; c += 256) {
    float s  = stats1[c], ssq = stats1[CH1 + c];
    float mu  = s  * (1.0f / M_Q);
    float var = ssq * (1.0f / M_Q) - mu * mu;
    float r   = 1.0f / sqrtf(var + 1e-5f);
    float gg = g1[c], bb = b1[c];
    scs[c] = r * gg;
    shs[c] = bb - mu * r * gg;
  }
  st_s[tid >> 7][tid & 127] = 0.0f;
  __syncthreads();

  const int arow = tid >> 5;   // 0..7
  const int ak   = tid & 31;   // 0..31
  const int ry   = tid >> 6;   // 0..3 (uniform per wave -> broadcast A reads)
  const int cx   = tid & 63;   // 0..63

  float a00 = 0.f, a01 = 0.f, a10 = 0.f, a11 = 0.f;

  for (int k0 = 0; k0 < CH1; k0 += CBK) {
    float a = y1[(size_t)(m0 + arow) * CH1 + k0 + ak];
    As[ak][arow] = fmaxf(a * scs[k0 + ak] + shs[k0 + ak], 0.0f);
    #pragma unroll
    for (int jj = 0; jj < 4; jj++) {
      int fid = tid + jj * 256;
      int kk = fid >> 5, c4 = (fid & 31) * 4;
      *(float4*)&Bs[kk][c4] = *(const float4*)&w2T[(size_t)(k0 + kk) * CH2 + c4];
    }
    __syncthreads();

    #pragma unroll
    for (int kk = 0; kk < CBK; kk++) {
      float2 av = *(const float2*)&As[kk][ry * 2];
      float b0 = Bs[kk][cx], b1v = Bs[kk][cx + 64];
      a00 += av.x * b0; a01 += av.x * b1v;
      a10 += av.y * b0; a11 += av.y * b1v;
    }
    __syncthreads();
  }

  z[(size_t)(m0 + ry*2    ) * CH2 + cx     ] = a00;
  z[(size_t)(m0 + ry*2    ) * CH2 + cx + 64] = a01;
  z[(size_t)(m0 + ry*2 + 1) * CH2 + cx     ] = a10;
  z[(size_t)(m0 + ry*2 + 1) * CH2 + cx + 64] = a11;

  atomicAdd(&st_s[0][cx     ], a00 + a10);
  atomicAdd(&st_s[0][cx + 64], a01 + a11);
  atomicAdd(&st_s[1][cx     ], a00*a00 + a10*a10);
  atomicAdd(&st_s[1][cx + 64], a01*a01 + a11*a11);
  __syncthreads();
  // spread global atomics over 8 copies to cut same-address contention 8x
  atomicAdd(&stats2[(blockIdx.x & 7) * 256 + tid], st_s[tid >> 7][tid & 127]);
}

// ---------------- Kernel D: BN2 apply + ReLU -> f32 out ----------------
__global__ void kD(const float* __restrict__ z,
                   const float* __restrict__ stats2,   // [8][256]
                   const float* __restrict__ g2,
                   const float* __restrict__ b2,
                   float* __restrict__ out)
{
  int t = blockIdx.x * 256 + threadIdx.x;
  if (t >= M_Q * CH2) return;
  int c = t & 127;
  float s = 0.0f, ss = 0.0f;
  #pragma unroll
  for (int k = 0; k < 8; k++) {
    s  += stats2[k * 256 + c];
    ss += stats2[k * 256 + 128 + c];
  }
  float mu  = s  * (1.0f / M_Q);
  float var = ss * (1.0f / M_Q) - mu * mu;
  float r   = 1.0f / sqrtf(var + 1e-5f);
  float val = fmaxf((z[t] - mu) * r * g2[c] + b2[c], 0.0f);
  out[t] = val;
}

extern "C" void kernel_launch(void* const* d_in, const int* in_sizes, int n_in,
                              void* d_out, int out_size, void* d_ws, size_t ws_size,
                              hipStream_t stream)
{
  const float* sup_xyz  = (const float*)d_in[0];
  const float* sup_feat = (const float*)d_in[1];
  const float* new_xyz  = (const float*)d_in[2];
  const float* w1       = (const float*)d_in[3];
  const float* g1       = (const float*)d_in[4];
  const float* b1       = (const float*)d_in[5];
  const float* w2       = (const float*)d_in[6];
  const float* g2       = (const float*)d_in[7];
  const float* b2       = (const float*)d_in[8];
  float* out = (float*)d_out;

  char* ws = (char*)d_ws;
  float* y1     = (float*)(ws);                       // 14,155,776 B
  float* z      = (float*)(ws + 14155776);            //  2,097,152 B (aliased by w1T early)
  float* w2T    = (float*)(ws + 16252928);            //    442,368 B
  float* stats  = (float*)(ws + 16695296);            //     15,104 B (1728 + 2048 f32)
  int*   counts = (int*)  (ws + 16710400);            //        576 B
  int*   cursor = (int*)  (ws + 16710976);            //        576 B
  int*   starts = (int*)  (ws + 16711552);            //        580 B
  float* xs     = (float*)(ws + 16712132);            //     65,536 B
  float* ys     = (float*)(ws + 16777668);
  float* zs     = (float*)(ws + 16843204);
  int*   sid    = (int*)  (ws + 16908740);
  float* nnW    = (float*)(ws + 16974276);            //  1,327,104 B
  int*   nnGI   = (int*)  (ws + 18301380);            //  1,327,104 B
  float* nnLX   = (float*)(ws + 19628484);            //  3,981,312 B  (end 23,609,796)
  float* stats1 = stats;
  float* stats2 = stats + 2 * CH1;                    // 8 copies x 256
  // w1T (141,696 B) aliases z: kA3 (last reader) runs before kC (writer of z).
  float* w1T    = z;

  // zero stats + counts + cursor in one contiguous memset
  hipMemsetAsync(stats, 0, 15104 + 576 + 576, stream);

  const int WT_TOT = CIN*CH1 + CH1*CH2;
  hipLaunchKernelGGL(kWT,     dim3((WT_TOT + 255) / 256), dim3(256), 0, stream, w1, w1T, w2, w2T);
  hipLaunchKernelGGL(kCount,  dim3((N_SUP + 255) / 256),  dim3(256), 0, stream, sup_xyz, counts);
  hipLaunchKernelGGL(kScan,   dim3(1),                    dim3(256), 0, stream, counts, starts, cursor);
  hipLaunchKernelGGL(kScatter,dim3((N_SUP + 255) / 256),  dim3(256), 0, stream, sup_xyz, cursor, xs, ys, zs, sid);
  hipLaunchKernelGGL(kA12,    dim3(M_Q),                  dim3(256), 0, stream, xs, ys, zs, sid, starts, new_xyz, sup_xyz, nnW, nnGI, nnLX);
  hipLaunchKernelGGL(kA3,     dim3(M_Q / 8),              dim3(256), 0, stream, sup_feat, nnW, nnGI, nnLX, w1T, y1);
  hipLaunchKernelGGL(kB,      dim3(M_Q / 64),             dim3(CH1), 0, stream, y1, stats1);
  hipLaunchKernelGGL(kC,      dim3(M_Q / CBM),            dim3(256), 0, stream, y1, stats1, g1, b1, w2T, z, stats2);
  hipLaunchKernelGGL(kD,      dim3((M_Q*CH2 + 255) / 256),dim3(256), 0, stream, z, stats2, g2, b2, out);
}

// Round 9
// 190.539 us; speedup vs baseline: 1.2840x; 1.2840x over previous
//
#include <hip/hip_runtime.h>
#include <hip/hip_bf16.h>

#define N_SUP 16384
#define M_Q   4096
#define TV    27
#define CIN   41
#define CH1   864
#define CH2   128
#define CAP   1024
#define NB    12          // bins per xy axis (width 50/12 = 4.17 >= 4)
#define NRING 16          // dq rings of width 0.5 (covers cube diagonal 6.93)

// kC tiling: BM=8 rows, BN=128 cols, BK=32, 2x2 per thread, grid 512 -> 2 blocks/CU
#define CBM 8
#define CBK 32

// grid offset value for axis-index 0/1/2 : linspace(-R+R/NV, R-R/NV, 3) = {-1.3333334, 0, +1.3333334}
__device__ __forceinline__ float gsel(int i){
  const float GOFF = (float)(-2.0 + 2.0 / 3.0);   // -1.3333334f (matches f32 linspace endpoint)
  return (i == 0) ? GOFF : ((i == 2) ? -GOFF : 0.0f);
}

__device__ __forceinline__ int binOf(float x){
  int b = (int)(x * (float)(NB / 50.0));
  return (b < 0) ? 0 : ((b > NB - 1) ? NB - 1 : b);
}

// branchless 3-deep insert of u64 key (keeps k0 <= k1 <= k2)
__device__ __forceinline__ void insK(unsigned long long key,
                                     unsigned long long& k0,
                                     unsigned long long& k1,
                                     unsigned long long& k2){
  bool b0 = key < k0, b1 = key < k1, b2 = key < k2;
  k2 = b1 ? k1 : (b2 ? key : k2);
  k1 = b0 ? k0 : (b1 ? key : k1);
  k0 = b0 ? key : k0;
}

// ---------------- Kernel WT: transpose w1 and w2 ----------------
__global__ void kWT(const float* __restrict__ w1, float* __restrict__ w1T,
                    const float* __restrict__ w2, float* __restrict__ w2T)
{
  int idx = blockIdx.x * 256 + threadIdx.x;
  if (idx < CIN * CH1) {
    int k = idx / CH1, t = idx % CH1;
    w1T[idx] = w1[(size_t)t * CIN + k];
  }
  int j = idx - CIN * CH1;
  if (j >= 0 && j < CH1 * CH2) {
    int k = j / CH2, c = j % CH2;
    w2T[j] = w2[(size_t)c * CH1 + k];
  }
}

// ---------------- binning: count / scan / scatter ----------------
__global__ void kCount(const float* __restrict__ sup_xyz, int* __restrict__ counts)
{
  int i = blockIdx.x * 256 + threadIdx.x;
  if (i < N_SUP) {
    float x = sup_xyz[3*i], y = sup_xyz[3*i+1];
    atomicAdd(&counts[binOf(x) * NB + binOf(y)], 1);
  }
}

__global__ void kScan(const int* __restrict__ counts, int* __restrict__ starts, int* __restrict__ cursor)
{
  __shared__ int sc[NB*NB];
  int t = threadIdx.x;
  if (t < NB*NB) sc[t] = counts[t];
  __syncthreads();
  if (t == 0) {
    int acc = 0;
    for (int b = 0; b < NB*NB; b++) { int c = sc[b]; sc[b] = acc; acc += c; }
  }
  __syncthreads();
  if (t < NB*NB) { starts[t] = sc[t]; cursor[t] = sc[t]; }
  if (t == NB*NB) starts[NB*NB] = N_SUP;
}

__global__ void kScatter(const float* __restrict__ sup_xyz, int* __restrict__ cursor,
                         float* __restrict__ xs, float* __restrict__ ys,
                         float* __restrict__ zs, int* __restrict__ sid)
{
  int i = blockIdx.x * 256 + threadIdx.x;
  if (i < N_SUP) {
    float x = sup_xyz[3*i], y = sup_xyz[3*i+1], z = sup_xyz[3*i+2];
    int b = binOf(x) * NB + binOf(y);
    int p = atomicAdd(&cursor[b], 1);
    xs[p] = x; ys[p] = y; zs[p] = z; sid[p] = i;
  }
}

// ---------------- Kernel A12: cube filter + O(n) ring sort + pruned per-voxel 3NN ----------------
__global__ __launch_bounds__(256) void kA12(const float* __restrict__ xs,
                                            const float* __restrict__ ys,
                                            const float* __restrict__ zs,
                                            const int*   __restrict__ sid,
                                            const int*   __restrict__ starts,
                                            const float* __restrict__ new_xyz,
                                            const float* __restrict__ sup_xyz,
                                            float* __restrict__ nnW,
                                            int*   __restrict__ nnGI,
                                            float* __restrict__ nnLX)
{
  __shared__ float4 cxyz[CAP];                 // filtered candidates (.w = sid bits)
  __shared__ float4 sxyz[CAP];                 // ring-sorted candidates
  __shared__ unsigned char cring[CAP];
  __shared__ int rbeg[NRING + 1];
  __shared__ int rcnt[NRING];
  __shared__ int rcur[NRING];
  __shared__ unsigned long long sk[TV][8][3];
  __shared__ int s_cnt;

  const int m   = blockIdx.x;
  const int tid = threadIdx.x;
  if (tid == 0) s_cnt = 0;
  if (tid < NRING) rcnt[tid] = 0;
  __syncthreads();

  const float qx = new_xyz[m*3+0];
  const float qy = new_xyz[m*3+1];
  const float qz = new_xyz[m*3+2];

  // ---- phase 1: cube filter over <=3x3 bins (z-test vacuous: |dz|<4 always) ----
  const int bx0 = binOf(qx - 4.0f), bx1 = binOf(qx + 4.0f);
  const int by0 = binOf(qy - 4.0f), by1 = binOf(qy + 4.0f);
  for (int bx = bx0; bx <= bx1; bx++) {
    const int beg = starts[bx * NB + by0];
    const int end = starts[bx * NB + by1 + 1];
    for (int i = beg + tid; i < end; i += 256) {
      float x = xs[i], y = ys[i];
      if (fabsf(__fsub_rn(x, qx)) <= 4.0f && fabsf(__fsub_rn(y, qy)) <= 4.0f) {
        int p = atomicAdd(&s_cnt, 1);
        if (p < CAP) cxyz[p] = make_float4(x, y, zs[i], __uint_as_float((unsigned)sid[i]));
      }
    }
  }
  __syncthreads();
  const int cnt = (s_cnt < CAP) ? s_cnt : CAP;

  // ---- phase 1.5a: ring id (dq bucket, width 0.5) + count ----
  for (int i = tid; i < cnt; i += 256) {
    float4 f4 = cxyz[i];
    float dx = qx - f4.x, dy = qy - f4.y, dz = qz - f4.z;  // bound metric: any rounding ok
    float dq = sqrtf(dx*dx + dy*dy + dz*dz);
    int r = (int)(dq * 2.0f);
    r = (r < 0) ? 0 : ((r > NRING-1) ? NRING-1 : r);
    cring[i] = (unsigned char)r;
    atomicAdd(&rcnt[r], 1);
  }
  __syncthreads();
  // ---- phase 1.5b: 16-entry prefix ----
  if (tid == 0) {
    int acc = 0;
    #pragma unroll
    for (int r = 0; r < NRING; r++) { rbeg[r] = acc; rcur[r] = acc; acc += rcnt[r]; }
    rbeg[NRING] = acc;
  }
  __syncthreads();
  // ---- phase 1.5c: scatter into ring order ----
  for (int i = tid; i < cnt; i += 256) {
    int p = atomicAdd(&rcur[(int)cring[i]], 1);
    sxyz[p] = cxyz[i];
  }
  __syncthreads();

  // ---- phase 2a: ring-ordered scan, 8 threads/voxel, provable early break ----
  const int v = tid >> 3, j = tid & 7;
  if (v < TV) {
    const float ox = gsel(v / 9), oy = gsel((v / 3) % 3), oz = gsel(v % 3);
    const float gx = qx + ox, gy = qy + oy, gz = qz + oz;
    const float dgq = sqrtf(ox*ox + oy*oy + oz*oz) + 1e-3f;   // conservative |g-q|

    unsigned long long k0 = ~0ull, k1 = ~0ull, k2 = ~0ull;
    float k2df = __uint_as_float(0xFFFFFFFFu);   // NaN sentinel -> no reject/break
    for (int r = 0; r < NRING; r++) {
      float t = (r * 0.5f - 1e-3f) - dgq;        // min possible dist(ring member, g)
      if (t > 0.0f && t * t > k2df * 1.000001f) break;   // NaN -> false
      const int rend = rbeg[r + 1];
      for (int c = rbeg[r] + j; c < rend; c += 8) {
        float4 f4 = sxyz[c];
        float dx = __fsub_rn(gx, f4.x);
        float dy = __fsub_rn(gy, f4.y);
        float dz = __fsub_rn(gz, f4.z);
        // forbid FMA contraction: must match numpy f32 (mul, mul, add, mul, add)
        float dd = __fadd_rn(__fadd_rn(__fmul_rn(dx,dx), __fmul_rn(dy,dy)), __fmul_rn(dz,dz));
        if (!(dd > k2df)) {                      // fast reject; NaN -> take insert path
          unsigned long long key = ((unsigned long long)__float_as_uint(dd) << 32)
                                 | (unsigned long long)__float_as_uint(f4.w); // low = sid
          insK(key, k0, k1, k2);
          k2df = __uint_as_float((unsigned)(k2 >> 32));
        }
      }
    }
    sk[v][j][0] = k0; sk[v][j][1] = k1; sk[v][j][2] = k2;
  }
  __syncthreads();

  // ---- phase 2b: merge 8x3 keys per voxel + emit (threads 0..26) ----
  if (tid < TV) {
    const int vv = tid;
    const float gx = qx + gsel(vv / 9);
    const float gy = qy + gsel((vv / 3) % 3);
    const float gz = qz + gsel(vv % 3);
    unsigned long long k0 = ~0ull, k1 = ~0ull, k2 = ~0ull;
    #pragma unroll
    for (int jj = 0; jj < 8; jj++) {
      insK(sk[vv][jj][0], k0, k1, k2);
      insK(sk[vv][jj][1], k0, k1, k2);
      insK(sk[vv][jj][2], k0, k1, k2);
    }
    const int base = m * TV + vv;
    if (cnt > 0) {
      unsigned long long ks[3] = {k0, k1, k2};
      float d[3]; int gi[3]; bool ok[3];
      #pragma unroll
      for (int r = 0; r < 3; r++) {
        unsigned db = (unsigned)(ks[r] >> 32);
        ok[r] = (db != 0xFFFFFFFFu);
        d[r]  = ok[r] ? __uint_as_float(db) : 1e10f;
        gi[r] = ok[r] ? (int)(unsigned)(ks[r] & 0xFFFFFFFFull) : 0;
      }
      float r0 = 1.0f / (d[0] + 1e-8f);
      float r1 = 1.0f / (d[1] + 1e-8f);
      float r2 = 1.0f / (d[2] + 1e-8f);
      float den = fmaxf(r0 + r1 + r2, 1e-8f);
      nnW[base*3+0] = r0 / den; nnW[base*3+1] = r1 / den; nnW[base*3+2] = r2 / den;
      nnGI[base*3+0] = gi[0]; nnGI[base*3+1] = gi[1]; nnGI[base*3+2] = gi[2];
      #pragma unroll
      for (int r = 0; r < 3; r++) {
        if (ok[r]) {
          nnLX[base*9 + r*3 + 0] = gx - sup_xyz[gi[r]*3 + 0];
          nnLX[base*9 + r*3 + 1] = gy - sup_xyz[gi[r]*3 + 1];
          nnLX[base*9 + r*3 + 2] = gz - sup_xyz[gi[r]*3 + 2];
        } else {
          nnLX[base*9 + r*3 + 0] = 0.0f;
          nnLX[base*9 + r*3 + 1] = 0.0f;
          nnLX[base*9 + r*3 + 2] = 0.0f;
        }
      }
    } else {
      #pragma unroll
      for (int r = 0; r < 3; r++) {
        nnW[base*3+r] = 0.0f; nnGI[base*3+r] = 0;
        nnLX[base*9+r*3+0] = 0.0f; nnLX[base*9+r*3+1] = 0.0f; nnLX[base*9+r*3+2] = 0.0f;
      }
    }
  }
}

// ---------------- Kernel A3: interp features + grouped conv1, 8 queries per block ----------------
__global__ __launch_bounds__(256) void kA3(const float* __restrict__ sup_feat,
                                           const float* __restrict__ nnW,
                                           const int*   __restrict__ nnGI,
                                           const float* __restrict__ nnLX,
                                           const float* __restrict__ w1T,
                                           float* __restrict__ y1)
{
  __shared__ float s_feats[8][TV][CIN];
  __shared__ float s_w[8][TV][3];
  __shared__ int   s_gi[8][TV][3];

  const int m0  = blockIdx.x * 8;
  const int tid = threadIdx.x;

  for (int t = tid; t < 8*TV*3; t += 256) {
    int q = t / (TV*3), rem = t % (TV*3);
    s_w[q][rem/3][rem%3]  = nnW[m0*TV*3 + t];
    s_gi[q][rem/3][rem%3] = nnGI[m0*TV*3 + t];
  }
  for (int t = tid; t < 8*TV*9; t += 256) {
    int q = t / (TV*9), rem = t % (TV*9);
    s_feats[q][rem/9][32 + rem%9] = nnLX[m0*TV*9 + t];
  }
  __syncthreads();

  for (int t = tid; t < 8*TV*32; t += 256) {
    const int q = t / (TV*32), rem = t % (TV*32);
    const int v = rem >> 5, ch = rem & 31;
    s_feats[q][v][ch] = s_w[q][v][0] * sup_feat[s_gi[q][v][0]*32 + ch]
                      + s_w[q][v][1] * sup_feat[s_gi[q][v][1]*32 + ch]
                      + s_w[q][v][2] * sup_feat[s_gi[q][v][2]*32 + ch];
  }
  __syncthreads();

  for (int t = tid; t < CH1; t += 256) {
    const int v = t >> 5;
    float acc[8];
    #pragma unroll
    for (int q = 0; q < 8; q++) acc[q] = 0.0f;
    for (int k = 0; k < CIN; k++) {
      float w = w1T[k * CH1 + t];
      #pragma unroll
      for (int q = 0; q < 8; q++) acc[q] += s_feats[q][v][k] * w;
    }
    #pragma unroll
    for (int q = 0; q < 8; q++) y1[(size_t)(m0 + q) * CH1 + t] = acc[q];
  }
}

// ---------------- Kernel B: BN1 stats ----------------
__global__ void kB(const float* __restrict__ y1, float* __restrict__ stats1)
{
  const int c  = threadIdx.x;        // 864 threads
  const int m0 = blockIdx.x * 64;    // 64 blocks
  float s = 0.0f, ss = 0.0f;
  for (int r = 0; r < 64; r++) {
    float v = y1[(size_t)(m0 + r) * CH1 + c];
    s += v; ss += v * v;
  }
  atomicAdd(&stats1[c],       s);
  atomicAdd(&stats1[CH1 + c], ss);
}

// ---------------- Kernel C: BN1-fused GEMM, BM=8 x BN=128, 2x2/thread, grid 512 ----------------
__global__ __launch_bounds__(256) void kC(const float* __restrict__ y1,
                                          const float* __restrict__ stats1,
                                          const float* __restrict__ g1,
                                          const float* __restrict__ b1,
                                          const float* __restrict__ w2T,
                                          float* __restrict__ z,
                                          float* __restrict__ stats2)   // [8][256]
{
  __shared__ float As[CBK][10];        // stride 10: conflict-free, 8B-aligned rows
  __shared__ float Bs[CBK][CH2];       // 16 KB
  __shared__ float scs[CH1], shs[CH1]; // 6.9 KB
  __shared__ float st_s[2][CH2];       // 1 KB

  const int tid = threadIdx.x;
  const int m0  = blockIdx.x * CBM;

  for (int c = tid; c < CH1; c += 256) {
    float s  = stats1[c], ssq = stats1[CH1 + c];
    float mu  = s  * (1.0f / M_Q);
    float var = ssq * (1.0f / M_Q) - mu * mu;
    float r   = 1.0f / sqrtf(var + 1e-5f);
    float gg = g1[c], bb = b1[c];
    scs[c] = r * gg;
    shs[c] = bb - mu * r * gg;
  }
  st_s[tid >> 7][tid & 127] = 0.0f;
  __syncthreads();

  const int arow = tid >> 5;   // 0..7
  const int ak   = tid & 31;   // 0..31
  const int ry   = tid >> 6;   // 0..3 (uniform per wave -> broadcast A reads)
  const int cx   = tid & 63;   // 0..63

  float a00 = 0.f, a01 = 0.f, a10 = 0.f, a11 = 0.f;

  for (int k0 = 0; k0 < CH1; k0 += CBK) {
    float a = y1[(size_t)(m0 + arow) * CH1 + k0 + ak];
    As[ak][arow] = fmaxf(a * scs[k0 + ak] + shs[k0 + ak], 0.0f);
    #pragma unroll
    for (int jj = 0; jj < 4; jj++) {
      int fid = tid + jj * 256;
      int kk = fid >> 5, c4 = (fid & 31) * 4;
      *(float4*)&Bs[kk][c4] = *(const float4*)&w2T[(size_t)(k0 + kk) * CH2 + c4];
    }
    __syncthreads();

    #pragma unroll
    for (int kk = 0; kk < CBK; kk++) {
      float2 av = *(const float2*)&As[kk][ry * 2];
      float b0 = Bs[kk][cx], b1v = Bs[kk][cx + 64];
      a00 += av.x * b0; a01 += av.x * b1v;
      a10 += av.y * b0; a11 += av.y * b1v;
    }
    __syncthreads();
  }

  z[(size_t)(m0 + ry*2    ) * CH2 + cx     ] = a00;
  z[(size_t)(m0 + ry*2    ) * CH2 + cx + 64] = a01;
  z[(size_t)(m0 + ry*2 + 1) * CH2 + cx     ] = a10;
  z[(size_t)(m0 + ry*2 + 1) * CH2 + cx + 64] = a11;

  atomicAdd(&st_s[0][cx     ], a00 + a10);
  atomicAdd(&st_s[0][cx + 64], a01 + a11);
  atomicAdd(&st_s[1][cx     ], a00*a00 + a10*a10);
  atomicAdd(&st_s[1][cx + 64], a01*a01 + a11*a11);
  __syncthreads();
  // spread global atomics over 8 copies to cut same-address contention 8x
  atomicAdd(&stats2[(blockIdx.x & 7) * 256 + tid], st_s[tid >> 7][tid & 127]);
}

// ---------------- Kernel D: BN2 apply + ReLU -> f32 out ----------------
__global__ void kD(const float* __restrict__ z,
                   const float* __restrict__ stats2,   // [8][256]
                   const float* __restrict__ g2,
                   const float* __restrict__ b2,
                   float* __restrict__ out)
{
  int t = blockIdx.x * 256 + threadIdx.x;
  if (t >= M_Q * CH2) return;
  int c = t & 127;
  float s = 0.0f, ss = 0.0f;
  #pragma unroll
  for (int k = 0; k < 8; k++) {
    s  += stats2[k * 256 + c];
    ss += stats2[k * 256 + 128 + c];
  }
  float mu  = s  * (1.0f / M_Q);
  float var = ss * (1.0f / M_Q) - mu * mu;
  float r   = 1.0f / sqrtf(var + 1e-5f);
  float val = fmaxf((z[t] - mu) * r * g2[c] + b2[c], 0.0f);
  out[t] = val;
}

extern "C" void kernel_launch(void* const* d_in, const int* in_sizes, int n_in,
                              void* d_out, int out_size, void* d_ws, size_t ws_size,
                              hipStream_t stream)
{
  const float* sup_xyz  = (const float*)d_in[0];
  const float* sup_feat = (const float*)d_in[1];
  const float* new_xyz  = (const float*)d_in[2];
  const float* w1       = (const float*)d_in[3];
  const float* g1       = (const float*)d_in[4];
  const float* b1       = (const float*)d_in[5];
  const float* w2       = (const float*)d_in[6];
  const float* g2       = (const float*)d_in[7];
  const float* b2       = (const float*)d_in[8];
  float* out = (float*)d_out;

  char* ws = (char*)d_ws;
  float* y1     = (float*)(ws);                       // 14,155,776 B
  float* z      = (float*)(ws + 14155776);            //  2,097,152 B (aliased by w1T early)
  float* w2T    = (float*)(ws + 16252928);            //    442,368 B
  float* stats  = (float*)(ws + 16695296);            //     15,104 B (1728 + 2048 f32)
  int*   counts = (int*)  (ws + 16710400);            //        576 B
  int*   cursor = (int*)  (ws + 16710976);            //        576 B
  int*   starts = (int*)  (ws + 16711552);            //        580 B
  float* xs     = (float*)(ws + 16712132);            //     65,536 B
  float* ys     = (float*)(ws + 16777668);
  float* zs     = (float*)(ws + 16843204);
  int*   sid    = (int*)  (ws + 16908740);
  float* nnW    = (float*)(ws + 16974276);            //  1,327,104 B
  int*   nnGI   = (int*)  (ws + 18301380);            //  1,327,104 B
  float* nnLX   = (float*)(ws + 19628484);            //  3,981,312 B  (end 23,609,796)
  float* stats1 = stats;
  float* stats2 = stats + 2 * CH1;                    // 8 copies x 256
  // w1T (141,696 B) aliases z: kA3 (last reader) runs before kC (writer of z).
  float* w1T    = z;

  // zero stats + counts + cursor in one contiguous memset
  hipMemsetAsync(stats, 0, 15104 + 576 + 576, stream);

  const int WT_TOT = CIN*CH1 + CH1*CH2;
  hipLaunchKernelGGL(kWT,     dim3((WT_TOT + 255) / 256), dim3(256), 0, stream, w1, w1T, w2, w2T);
  hipLaunchKernelGGL(kCount,  dim3((N_SUP + 255) / 256),  dim3(256), 0, stream, sup_xyz, counts);
  hipLaunchKernelGGL(kScan,   dim3(1),                    dim3(256), 0, stream, counts, starts, cursor);
  hipLaunchKernelGGL(kScatter,dim3((N_SUP + 255) / 256),  dim3(256), 0, stream, sup_xyz, cursor, xs, ys, zs, sid);
  hipLaunchKernelGGL(kA12,    dim3(M_Q),                  dim3(256), 0, stream, xs, ys, zs, sid, starts, new_xyz, sup_xyz, nnW, nnGI, nnLX);
  hipLaunchKernelGGL(kA3,     dim3(M_Q / 8),              dim3(256), 0, stream, sup_feat, nnW, nnGI, nnLX, w1T, y1);
  hipLaunchKernelGGL(kB,      dim3(M_Q / 64),             dim3(CH1), 0, stream, y1, stats1);
  hipLaunchKernelGGL(kC,      dim3(M_Q / CBM),            dim3(256), 0, stream, y1, stats1, g1, b1, w2T, z, stats2);
  hipLaunchKernelGGL(kD,      dim3((M_Q*CH2 + 255) / 256),dim3(256), 0, stream, z, stats2, g2, b2, out);
}

// Round 10
// 179.180 us; speedup vs baseline: 1.3654x; 1.0634x over previous
//
#include <hip/hip_runtime.h>
#include <hip/hip_bf16.h>

#define N_SUP 16384
#define M_Q   4096
#define TV    27
#define CIN   41
#define CH1   864
#define CH2   128
#define CAP   1024
#define NB    12          // bins per xy axis (width 50/12 = 4.17 >= 4)

// grid offset value for axis-index 0/1/2 : linspace(-R+R/NV, R-R/NV, 3) = {-1.3333334, 0, +1.3333334}
__device__ __forceinline__ float gsel(int i){
  const float GOFF = (float)(-2.0 + 2.0 / 3.0);   // -1.3333334f (matches f32 linspace endpoint)
  return (i == 0) ? GOFF : ((i == 2) ? -GOFF : 0.0f);
}

__device__ __forceinline__ int binOf(float x){
  int b = (int)(x * (float)(NB / 50.0));
  return (b < 0) ? 0 : ((b > NB - 1) ? NB - 1 : b);
}

// branchless 3-deep insert of u64 key (keeps k0 <= k1 <= k2)
__device__ __forceinline__ void insK(unsigned long long key,
                                     unsigned long long& k0,
                                     unsigned long long& k1,
                                     unsigned long long& k2){
  bool b0 = key < k0, b1 = key < k1, b2 = key < k2;
  k2 = b1 ? k1 : (b2 ? key : k2);
  k1 = b0 ? k0 : (b1 ? key : k1);
  k0 = b0 ? key : k0;
}

// ---------------- Kernel WT: transpose w1 and w2 ----------------
__global__ void kWT(const float* __restrict__ w1, float* __restrict__ w1T,
                    const float* __restrict__ w2, float* __restrict__ w2T)
{
  int idx = blockIdx.x * 256 + threadIdx.x;
  if (idx < CIN * CH1) {
    int k = idx / CH1, t = idx % CH1;
    w1T[idx] = w1[(size_t)t * CIN + k];
  }
  int j = idx - CIN * CH1;
  if (j >= 0 && j < CH1 * CH2) {
    int k = j / CH2, c = j % CH2;
    w2T[j] = w2[(size_t)c * CH1 + k];
  }
}

// ---------------- binning: count / scan / scatter ----------------
__global__ void kCount(const float* __restrict__ sup_xyz, int* __restrict__ counts)
{
  int i = blockIdx.x * 256 + threadIdx.x;
  if (i < N_SUP) {
    float x = sup_xyz[3*i], y = sup_xyz[3*i+1];
    atomicAdd(&counts[binOf(x) * NB + binOf(y)], 1);
  }
}

__global__ void kScan(const int* __restrict__ counts, int* __restrict__ starts, int* __restrict__ cursor)
{
  __shared__ int sc[NB*NB];
  int t = threadIdx.x;
  if (t < NB*NB) sc[t] = counts[t];
  __syncthreads();
  if (t == 0) {
    int acc = 0;
    for (int b = 0; b < NB*NB; b++) { int c = sc[b]; sc[b] = acc; acc += c; }
  }
  __syncthreads();
  if (t < NB*NB) { starts[t] = sc[t]; cursor[t] = sc[t]; }
  if (t == NB*NB) starts[NB*NB] = N_SUP;
}

__global__ void kScatter(const float* __restrict__ sup_xyz, int* __restrict__ cursor,
                         float* __restrict__ xs, float* __restrict__ ys,
                         float* __restrict__ zs, int* __restrict__ sid)
{
  int i = blockIdx.x * 256 + threadIdx.x;
  if (i < N_SUP) {
    float x = sup_xyz[3*i], y = sup_xyz[3*i+1], z = sup_xyz[3*i+2];
    int b = binOf(x) * NB + binOf(y);
    int p = atomicAdd(&cursor[b], 1);
    xs[p] = x; ys[p] = y; zs[p] = z; sid[p] = i;
  }
}

// ---------------- Kernel A12: bin-pruned cube filter + per-voxel 3NN (guarded insert) ----------------
__global__ __launch_bounds__(256) void kA12(const float* __restrict__ xs,
                                            const float* __restrict__ ys,
                                            const float* __restrict__ zs,
                                            const int*   __restrict__ sid,
                                            const int*   __restrict__ starts,
                                            const float* __restrict__ new_xyz,
                                            const float* __restrict__ sup_xyz,
                                            float* __restrict__ nnW,
                                            int*   __restrict__ nnGI,
                                            float* __restrict__ nnLX)
{
  __shared__ float4 cxyz[CAP];                 // filtered candidates (.w = sid bits)
  __shared__ unsigned long long sk[TV][8][3];
  __shared__ int s_cnt;

  const int m   = blockIdx.x;
  const int tid = threadIdx.x;
  if (tid == 0) s_cnt = 0;
  __syncthreads();

  const float qx = new_xyz[m*3+0];
  const float qy = new_xyz[m*3+1];
  const float qz = new_xyz[m*3+2];

  // ---- phase 1: cube filter over <=3x3 bins (z-test vacuous: |dz|<4 always) ----
  const int bx0 = binOf(qx - 4.0f), bx1 = binOf(qx + 4.0f);
  const int by0 = binOf(qy - 4.0f), by1 = binOf(qy + 4.0f);
  for (int bx = bx0; bx <= bx1; bx++) {
    const int beg = starts[bx * NB + by0];
    const int end = starts[bx * NB + by1 + 1];
    for (int i = beg + tid; i < end; i += 256) {
      float x = xs[i], y = ys[i];
      if (fabsf(__fsub_rn(x, qx)) <= 4.0f && fabsf(__fsub_rn(y, qy)) <= 4.0f) {
        int p = atomicAdd(&s_cnt, 1);
        if (p < CAP) cxyz[p] = make_float4(x, y, zs[i], __uint_as_float((unsigned)sid[i]));
      }
    }
  }
  __syncthreads();
  const int cnt = (s_cnt < CAP) ? s_cnt : CAP;

  // ---- phase 2a: strided scan, 8 threads per voxel, guarded insert ----
  const int v = tid >> 3, j = tid & 7;
  if (v < TV) {
    const float gx = qx + gsel(v / 9);
    const float gy = qy + gsel((v / 3) % 3);
    const float gz = qz + gsel(v % 3);
    unsigned long long k0 = ~0ull, k1 = ~0ull, k2 = ~0ull;
    float k2df = __uint_as_float(0xFFFFFFFFu);   // NaN sentinel -> insert path until 3 found
    for (int c = j; c < cnt; c += 8) {
      float4 f4 = cxyz[c];
      float dx = __fsub_rn(gx, f4.x);
      float dy = __fsub_rn(gy, f4.y);
      float dz = __fsub_rn(gz, f4.z);
      // forbid FMA contraction: must match numpy f32 (mul, mul, add, mul, add)
      float dd = __fadd_rn(__fadd_rn(__fmul_rn(dx,dx), __fmul_rn(dy,dy)), __fmul_rn(dz,dz));
      if (!(dd > k2df)) {                        // fast reject; == still takes insert (tie by sid)
        unsigned long long key = ((unsigned long long)__float_as_uint(dd) << 32)
                               | (unsigned long long)__float_as_uint(f4.w); // low = sid
        insK(key, k0, k1, k2);
        k2df = __uint_as_float((unsigned)(k2 >> 32));
      }
    }
    sk[v][j][0] = k0; sk[v][j][1] = k1; sk[v][j][2] = k2;
  }
  __syncthreads();

  // ---- phase 2b: merge 8x3 keys per voxel + emit (threads 0..26) ----
  if (tid < TV) {
    const int vv = tid;
    const float gx = qx + gsel(vv / 9);
    const float gy = qy + gsel((vv / 3) % 3);
    const float gz = qz + gsel(vv % 3);
    unsigned long long k0 = ~0ull, k1 = ~0ull, k2 = ~0ull;
    #pragma unroll
    for (int jj = 0; jj < 8; jj++) {
      insK(sk[vv][jj][0], k0, k1, k2);
      insK(sk[vv][jj][1], k0, k1, k2);
      insK(sk[vv][jj][2], k0, k1, k2);
    }
    const int base = m * TV + vv;
    if (cnt > 0) {
      unsigned long long ks[3] = {k0, k1, k2};
      float d[3]; int gi[3]; bool ok[3];
      #pragma unroll
      for (int r = 0; r < 3; r++) {
        unsigned db = (unsigned)(ks[r] >> 32);
        ok[r] = (db != 0xFFFFFFFFu);
        d[r]  = ok[r] ? __uint_as_float(db) : 1e10f;
        gi[r] = ok[r] ? (int)(unsigned)(ks[r] & 0xFFFFFFFFull) : 0;
      }
      float r0 = 1.0f / (d[0] + 1e-8f);
      float r1 = 1.0f / (d[1] + 1e-8f);
      float r2 = 1.0f / (d[2] + 1e-8f);
      float den = fmaxf(r0 + r1 + r2, 1e-8f);
      nnW[base*3+0] = r0 / den; nnW[base*3+1] = r1 / den; nnW[base*3+2] = r2 / den;
      nnGI[base*3+0] = gi[0]; nnGI[base*3+1] = gi[1]; nnGI[base*3+2] = gi[2];
      #pragma unroll
      for (int r = 0; r < 3; r++) {
        if (ok[r]) {
          nnLX[base*9 + r*3 + 0] = gx - sup_xyz[gi[r]*3 + 0];
          nnLX[base*9 + r*3 + 1] = gy - sup_xyz[gi[r]*3 + 1];
          nnLX[base*9 + r*3 + 2] = gz - sup_xyz[gi[r]*3 + 2];
        } else {
          nnLX[base*9 + r*3 + 0] = 0.0f;
          nnLX[base*9 + r*3 + 1] = 0.0f;
          nnLX[base*9 + r*3 + 2] = 0.0f;
        }
      }
    } else {
      #pragma unroll
      for (int r = 0; r < 3; r++) {
        nnW[base*3+r] = 0.0f; nnGI[base*3+r] = 0;
        nnLX[base*9+r*3+0] = 0.0f; nnLX[base*9+r*3+1] = 0.0f; nnLX[base*9+r*3+2] = 0.0f;
      }
    }
  }
}

// ---------------- Kernel A3: interp features + grouped conv1, 8 queries per block ----------------
__global__ __launch_bounds__(256) void kA3(const float* __restrict__ sup_feat,
                                           const float* __restrict__ nnW,
                                           const int*   __restrict__ nnGI,
                                           const float* __restrict__ nnLX,
                                           const float* __restrict__ w1T,
                                           float* __restrict__ y1)
{
  __shared__ float s_feats[8][TV][CIN];
  __shared__ float s_w[8][TV][3];
  __shared__ int   s_gi[8][TV][3];

  const int m0  = blockIdx.x * 8;
  const int tid = threadIdx.x;

  for (int t = tid; t < 8*TV*3; t += 256) {
    int q = t / (TV*3), rem = t % (TV*3);
    s_w[q][rem/3][rem%3]  = nnW[m0*TV*3 + t];
    s_gi[q][rem/3][rem%3] = nnGI[m0*TV*3 + t];
  }
  for (int t = tid; t < 8*TV*9; t += 256) {
    int q = t / (TV*9), rem = t % (TV*9);
    s_feats[q][rem/9][32 + rem%9] = nnLX[m0*TV*9 + t];
  }
  __syncthreads();

  for (int t = tid; t < 8*TV*32; t += 256) {
    const int q = t / (TV*32), rem = t % (TV*32);
    const int v = rem >> 5, ch = rem & 31;
    s_feats[q][v][ch] = s_w[q][v][0] * sup_feat[s_gi[q][v][0]*32 + ch]
                      + s_w[q][v][1] * sup_feat[s_gi[q][v][1]*32 + ch]
                      + s_w[q][v][2] * sup_feat[s_gi[q][v][2]*32 + ch];
  }
  __syncthreads();

  for (int t = tid; t < CH1; t += 256) {
    const int v = t >> 5;
    float acc[8];
    #pragma unroll
    for (int q = 0; q < 8; q++) acc[q] = 0.0f;
    for (int k = 0; k < CIN; k++) {
      float w = w1T[k * CH1 + t];
      #pragma unroll
      for (int q = 0; q < 8; q++) acc[q] += s_feats[q][v][k] * w;
    }
    #pragma unroll
    for (int q = 0; q < 8; q++) y1[(size_t)(m0 + q) * CH1 + t] = acc[q];
  }
}

// ---------------- Kernel B: BN1 stats ----------------
__global__ void kB(const float* __restrict__ y1, float* __restrict__ stats1)
{
  const int c  = threadIdx.x;        // 864 threads
  const int m0 = blockIdx.x * 64;    // 64 blocks
  float s = 0.0f, ss = 0.0f;
  for (int r = 0; r < 64; r++) {
    float v = y1[(size_t)(m0 + r) * CH1 + c];
    s += v; ss += v * v;
  }
  atomicAdd(&stats1[c],       s);
  atomicAdd(&stats1[CH1 + c], ss);
}

// ---------------- Kernel S: BN1 scale/shift precompute ----------------
__global__ void kS(const float* __restrict__ stats1,
                   const float* __restrict__ g1, const float* __restrict__ b1,
                   float* __restrict__ scsg, float* __restrict__ shsg)
{
  int c = blockIdx.x * 256 + threadIdx.x;
  if (c < CH1) {
    float s  = stats1[c], ssq = stats1[CH1 + c];
    float mu  = s  * (1.0f / M_Q);
    float var = ssq * (1.0f / M_Q) - mu * mu;
    float r   = 1.0f / sqrtf(var + 1e-5f);
    float gg = g1[c];
    scsg[c] = r * gg;
    shsg[c] = b1[c] - mu * r * gg;
  }
}

// ---------------- Kernel C: BN1-fused GEMM, 16x64 tile, 4x4/thread, 64-thr blocks, grid 512 ----------------
__global__ __launch_bounds__(64) void kC(const float* __restrict__ y1,
                                         const float* __restrict__ scsg,
                                         const float* __restrict__ shsg,
                                         const float* __restrict__ w2T,
                                         float* __restrict__ z,
                                         float* __restrict__ stats2)   // [8][256]
{
  __shared__ float As[32][20];     // transposed A-tile [k][row], stride 20 (16B-aligned rows)
  __shared__ float Bs[32][64];
  __shared__ float st_s[2][64];

  const int tid = threadIdx.x;
  const int m0  = (blockIdx.x >> 1) * 16;
  const int bn0 = (blockIdx.x & 1) * 64;

  st_s[0][tid] = 0.0f;
  st_s[1][tid] = 0.0f;

  const int tx = tid & 15;     // col group (4 cols)
  const int ty = tid >> 4;     // row group (4 rows)

  float4 pa[2], psc[2], psh[2], pb[8];
  #pragma unroll
  for (int s = 0; s < 2; s++) {
    int idx = tid + s*64; int row = idx & 15, kq = idx >> 4;
    pa[s]  = *(const float4*)&y1[(size_t)(m0 + row) * CH1 + kq*4];
    psc[s] = *(const float4*)&scsg[kq*4];
    psh[s] = *(const float4*)&shsg[kq*4];
  }
  #pragma unroll
  for (int s = 0; s < 8; s++) {
    int fid = tid + s*64; int kk = fid >> 4, c4 = (fid & 15)*4;
    pb[s] = *(const float4*)&w2T[(size_t)kk * CH2 + bn0 + c4];
  }

  float acc[4][4];
  #pragma unroll
  for (int i = 0; i < 4; i++)
    #pragma unroll
    for (int jj = 0; jj < 4; jj++) acc[i][jj] = 0.0f;

  for (int k0 = 0; k0 < CH1; k0 += 32) {
    // write staged regs to LDS (single-wave block: in-order LDS, no barrier needed)
    #pragma unroll
    for (int s = 0; s < 2; s++) {
      int idx = tid + s*64; int row = idx & 15, kq = idx >> 4;
      As[kq*4+0][row] = fmaxf(pa[s].x * psc[s].x + psh[s].x, 0.0f);
      As[kq*4+1][row] = fmaxf(pa[s].y * psc[s].y + psh[s].y, 0.0f);
      As[kq*4+2][row] = fmaxf(pa[s].z * psc[s].z + psh[s].z, 0.0f);
      As[kq*4+3][row] = fmaxf(pa[s].w * psc[s].w + psh[s].w, 0.0f);
    }
    #pragma unroll
    for (int s = 0; s < 8; s++) {
      int fid = tid + s*64; int kk = fid >> 4, c4 = (fid & 15)*4;
      *(float4*)&Bs[kk][c4] = pb[s];
    }
    // prefetch next k-tile into registers (overlaps with compute below)
    const int kn = k0 + 32;
    if (kn < CH1) {
      #pragma unroll
      for (int s = 0; s < 2; s++) {
        int idx = tid + s*64; int row = idx & 15, kq = idx >> 4;
        pa[s]  = *(const float4*)&y1[(size_t)(m0 + row) * CH1 + kn + kq*4];
        psc[s] = *(const float4*)&scsg[kn + kq*4];
        psh[s] = *(const float4*)&shsg[kn + kq*4];
      }
      #pragma unroll
      for (int s = 0; s < 8; s++) {
        int fid = tid + s*64; int kk = fid >> 4, c4 = (fid & 15)*4;
        pb[s] = *(const float4*)&w2T[(size_t)(kn + kk) * CH2 + bn0 + c4];
      }
    }
    // compute: 32 x (2 ds_read_b128 + 16 FMA)
    #pragma unroll
    for (int kk = 0; kk < 32; kk++) {
      float4 av = *(const float4*)&As[kk][ty*4];
      float4 bv = *(const float4*)&Bs[kk][tx*4];
      acc[0][0] += av.x*bv.x; acc[0][1] += av.x*bv.y; acc[0][2] += av.x*bv.z; acc[0][3] += av.x*bv.w;
      acc[1][0] += av.y*bv.x; acc[1][1] += av.y*bv.y; acc[1][2] += av.y*bv.z; acc[1][3] += av.y*bv.w;
      acc[2][0] += av.z*bv.x; acc[2][1] += av.z*bv.y; acc[2][2] += av.z*bv.z; acc[2][3] += av.z*bv.w;
      acc[3][0] += av.w*bv.x; acc[3][1] += av.w*bv.y; acc[3][2] += av.w*bv.z; acc[3][3] += av.w*bv.w;
    }
  }

  // epilogue: write z, reduce BN2 partial stats in LDS, then 2 global atomics/thread
  #pragma unroll
  for (int i = 0; i < 4; i++) {
    *(float4*)&z[(size_t)(m0 + ty*4 + i) * CH2 + bn0 + tx*4] =
        make_float4(acc[i][0], acc[i][1], acc[i][2], acc[i][3]);
  }
  #pragma unroll
  for (int jj = 0; jj < 4; jj++) {
    float s  = acc[0][jj] + acc[1][jj] + acc[2][jj] + acc[3][jj];
    float ss = acc[0][jj]*acc[0][jj] + acc[1][jj]*acc[1][jj]
             + acc[2][jj]*acc[2][jj] + acc[3][jj]*acc[3][jj];
    atomicAdd(&st_s[0][tx*4+jj], s);
    atomicAdd(&st_s[1][tx*4+jj], ss);
  }
  __syncthreads();
  const int copy = (blockIdx.x >> 1) & 7;
  atomicAdd(&stats2[copy*256 + bn0 + tid],       st_s[0][tid]);
  atomicAdd(&stats2[copy*256 + 128 + bn0 + tid], st_s[1][tid]);
}

// ---------------- Kernel D: BN2 apply + ReLU -> f32 out ----------------
__global__ void kD(const float* __restrict__ z,
                   const float* __restrict__ stats2,   // [8][256]
                   const float* __restrict__ g2,
                   const float* __restrict__ b2,
                   float* __restrict__ out)
{
  int t = blockIdx.x * 256 + threadIdx.x;
  if (t >= M_Q * CH2) return;
  int c = t & 127;
  float s = 0.0f, ss = 0.0f;
  #pragma unroll
  for (int k = 0; k < 8; k++) {
    s  += stats2[k * 256 + c];
    ss += stats2[k * 256 + 128 + c];
  }
  float mu  = s  * (1.0f / M_Q);
  float var = ss * (1.0f / M_Q) - mu * mu;
  float r   = 1.0f / sqrtf(var + 1e-5f);
  float val = fmaxf((z[t] - mu) * r * g2[c] + b2[c], 0.0f);
  out[t] = val;
}

extern "C" void kernel_launch(void* const* d_in, const int* in_sizes, int n_in,
                              void* d_out, int out_size, void* d_ws, size_t ws_size,
                              hipStream_t stream)
{
  const float* sup_xyz  = (const float*)d_in[0];
  const float* sup_feat = (const float*)d_in[1];
  const float* new_xyz  = (const float*)d_in[2];
  const float* w1       = (const float*)d_in[3];
  const float* g1       = (const float*)d_in[4];
  const float* b1       = (const float*)d_in[5];
  const float* w2       = (const float*)d_in[6];
  const float* g2       = (const float*)d_in[7];
  const float* b2       = (const float*)d_in[8];
  float* out = (float*)d_out;

  char* ws = (char*)d_ws;
  float* y1     = (float*)(ws);                       // 14,155,776 B
  float* z      = (float*)(ws + 14155776);            //  2,097,152 B (aliased by w1T early)
  float* w2T    = (float*)(ws + 16252928);            //    442,368 B
  float* stats  = (float*)(ws + 16695296);            //     15,104 B (1728 + 2048 f32)
  int*   counts = (int*)  (ws + 16710400);            //        576 B
  int*   cursor = (int*)  (ws + 16710976);            //        576 B
  int*   starts = (int*)  (ws + 16711552);            //        580 B
  float* xs     = (float*)(ws + 16712132);            //     65,536 B
  float* ys     = (float*)(ws + 16777668);
  float* zs     = (float*)(ws + 16843204);
  int*   sid    = (int*)  (ws + 16908740);
  float* nnW    = (float*)(ws + 16974276);            //  1,327,104 B
  int*   nnGI   = (int*)  (ws + 18301380);            //  1,327,104 B
  float* nnLX   = (float*)(ws + 19628484);            //  3,981,312 B  (end 23,609,796)
  float* stats1 = stats;
  float* stats2 = stats + 2 * CH1;                    // 8 copies x 256
  // w1T (141,696 B) aliases z: kA3 (last reader) runs before kC (writer of z).
  float* w1T    = z;
  // scsg/shsg (3456 B each) alias xs/ys: dead after kA12; kS rewrites before kC reads.
  float* scsg   = xs;
  float* shsg   = ys;

  // zero stats + counts + cursor in one contiguous memset
  hipMemsetAsync(stats, 0, 15104 + 576 + 576, stream);

  const int WT_TOT = CIN*CH1 + CH1*CH2;
  hipLaunchKernelGGL(kWT,     dim3((WT_TOT + 255) / 256), dim3(256), 0, stream, w1, w1T, w2, w2T);
  hipLaunchKernelGGL(kCount,  dim3((N_SUP + 255) / 256),  dim3(256), 0, stream, sup_xyz, counts);
  hipLaunchKernelGGL(kScan,   dim3(1),                    dim3(256), 0, stream, counts, starts, cursor);
  hipLaunchKernelGGL(kScatter,dim3((N_SUP + 255) / 256),  dim3(256), 0, stream, sup_xyz, cursor, xs, ys, zs, sid);
  hipLaunchKernelGGL(kA12,    dim3(M_Q),                  dim3(256), 0, stream, xs, ys, zs, sid, starts, new_xyz, sup_xyz, nnW, nnGI, nnLX);
  hipLaunchKernelGGL(kA3,     dim3(M_Q / 8),              dim3(256), 0, stream, sup_feat, nnW, nnGI, nnLX, w1T, y1);
  hipLaunchKernelGGL(kB,      dim3(M_Q / 64),             dim3(CH1), 0, stream, y1, stats1);
  hipLaunchKernelGGL(kS,      dim3((CH1 + 255) / 256),    dim3(256), 0, stream, stats1, g1, b1, scsg, shsg);
  hipLaunchKernelGGL(kC,      dim3((M_Q / 16) * 2),       dim3(64),  0, stream, y1, scsg, shsg, w2T, z, stats2);
  hipLaunchKernelGGL(kD,      dim3((M_Q*CH2 + 255) / 256),dim3(256), 0, stream, z, stats2, g2, b2, out);
}

// Round 11
// 163.610 us; speedup vs baseline: 1.4953x; 1.0952x over previous
//
#include <hip/hip_runtime.h>
#include <hip/hip_bf16.h>

#define N_SUP 16384
#define M_Q   4096
#define TV    27
#define CIN   41
#define CH1   864
#define CH2   128
#define CAP   1024
#define NB    12          // bins per xy axis (width 50/12 = 4.17 >= 4)

// kC tiling: 16x64 tile, 256 threads (4 waves), 2x2/thread, grid 512 -> 8 waves/CU
#define C2BM 16
#define C2BN 64
#define C2BK 32

// grid offset value for axis-index 0/1/2 : linspace(-R+R/NV, R-R/NV, 3) = {-1.3333334, 0, +1.3333334}
__device__ __forceinline__ float gsel(int i){
  const float GOFF = (float)(-2.0 + 2.0 / 3.0);   // -1.3333334f (matches f32 linspace endpoint)
  return (i == 0) ? GOFF : ((i == 2) ? -GOFF : 0.0f);
}

__device__ __forceinline__ int binOf(float x){
  int b = (int)(x * (float)(NB / 50.0));
  return (b < 0) ? 0 : ((b > NB - 1) ? NB - 1 : b);
}

// branchless 3-deep insert of u64 key (keeps k0 <= k1 <= k2)
__device__ __forceinline__ void insK(unsigned long long key,
                                     unsigned long long& k0,
                                     unsigned long long& k1,
                                     unsigned long long& k2){
  bool b0 = key < k0, b1 = key < k1, b2 = key < k2;
  k2 = b1 ? k1 : (b2 ? key : k2);
  k1 = b0 ? k0 : (b1 ? key : k1);
  k0 = b0 ? key : k0;
}

// ---------------- Kernel WT: transpose w1 and w2 ----------------
__global__ void kWT(const float* __restrict__ w1, float* __restrict__ w1T,
                    const float* __restrict__ w2, float* __restrict__ w2T)
{
  int idx = blockIdx.x * 256 + threadIdx.x;
  if (idx < CIN * CH1) {
    int k = idx / CH1, t = idx % CH1;
    w1T[idx] = w1[(size_t)t * CIN + k];
  }
  int j = idx - CIN * CH1;
  if (j >= 0 && j < CH1 * CH2) {
    int k = j / CH2, c = j % CH2;
    w2T[j] = w2[(size_t)c * CH1 + k];
  }
}

// ---------------- binning: count / scan / scatter ----------------
__global__ void kCount(const float* __restrict__ sup_xyz, int* __restrict__ counts)
{
  int i = blockIdx.x * 256 + threadIdx.x;
  if (i < N_SUP) {
    float x = sup_xyz[3*i], y = sup_xyz[3*i+1];
    atomicAdd(&counts[binOf(x) * NB + binOf(y)], 1);
  }
}

__global__ void kScan(const int* __restrict__ counts, int* __restrict__ starts, int* __restrict__ cursor)
{
  __shared__ int sc[NB*NB];
  int t = threadIdx.x;
  if (t < NB*NB) sc[t] = counts[t];
  __syncthreads();
  if (t == 0) {
    int acc = 0;
    for (int b = 0; b < NB*NB; b++) { int c = sc[b]; sc[b] = acc; acc += c; }
  }
  __syncthreads();
  if (t < NB*NB) { starts[t] = sc[t]; cursor[t] = sc[t]; }
  if (t == NB*NB) starts[NB*NB] = N_SUP;
}

__global__ void kScatter(const float* __restrict__ sup_xyz, int* __restrict__ cursor,
                         float* __restrict__ xs, float* __restrict__ ys,
                         float* __restrict__ zs, int* __restrict__ sid)
{
  int i = blockIdx.x * 256 + threadIdx.x;
  if (i < N_SUP) {
    float x = sup_xyz[3*i], y = sup_xyz[3*i+1], z = sup_xyz[3*i+2];
    int b = binOf(x) * NB + binOf(y);
    int p = atomicAdd(&cursor[b], 1);
    xs[p] = x; ys[p] = y; zs[p] = z; sid[p] = i;
  }
}

// ---------------- Kernel A12: bin-pruned cube filter + per-voxel 3NN (guarded insert) ----------------
__global__ __launch_bounds__(256) void kA12(const float* __restrict__ xs,
                                            const float* __restrict__ ys,
                                            const float* __restrict__ zs,
                                            const int*   __restrict__ sid,
                                            const int*   __restrict__ starts,
                                            const float* __restrict__ new_xyz,
                                            const float* __restrict__ sup_xyz,
                                            float* __restrict__ nnW,
                                            int*   __restrict__ nnGI,
                                            float* __restrict__ nnLX)
{
  __shared__ float4 cxyz[CAP];                 // filtered candidates (.w = sid bits)
  __shared__ unsigned long long sk[TV][8][3];
  __shared__ int s_cnt;

  const int m   = blockIdx.x;
  const int tid = threadIdx.x;
  if (tid == 0) s_cnt = 0;
  __syncthreads();

  const float qx = new_xyz[m*3+0];
  const float qy = new_xyz[m*3+1];
  const float qz = new_xyz[m*3+2];

  // ---- phase 1: cube filter over <=3x3 bins (z-test vacuous: |dz|<4 always) ----
  const int bx0 = binOf(qx - 4.0f), bx1 = binOf(qx + 4.0f);
  const int by0 = binOf(qy - 4.0f), by1 = binOf(qy + 4.0f);
  for (int bx = bx0; bx <= bx1; bx++) {
    const int beg = starts[bx * NB + by0];
    const int end = starts[bx * NB + by1 + 1];
    for (int i = beg + tid; i < end; i += 256) {
      float x = xs[i], y = ys[i];
      if (fabsf(__fsub_rn(x, qx)) <= 4.0f && fabsf(__fsub_rn(y, qy)) <= 4.0f) {
        int p = atomicAdd(&s_cnt, 1);
        if (p < CAP) cxyz[p] = make_float4(x, y, zs[i], __uint_as_float((unsigned)sid[i]));
      }
    }
  }
  __syncthreads();
  const int cnt = (s_cnt < CAP) ? s_cnt : CAP;

  // ---- phase 2a: strided scan, 8 threads per voxel, guarded insert ----
  const int v = tid >> 3, j = tid & 7;
  if (v < TV) {
    const float gx = qx + gsel(v / 9);
    const float gy = qy + gsel((v / 3) % 3);
    const float gz = qz + gsel(v % 3);
    unsigned long long k0 = ~0ull, k1 = ~0ull, k2 = ~0ull;
    float k2df = __uint_as_float(0xFFFFFFFFu);   // NaN sentinel -> insert path until 3 found
    for (int c = j; c < cnt; c += 8) {
      float4 f4 = cxyz[c];
      float dx = __fsub_rn(gx, f4.x);
      float dy = __fsub_rn(gy, f4.y);
      float dz = __fsub_rn(gz, f4.z);
      // forbid FMA contraction: must match numpy f32 (mul, mul, add, mul, add)
      float dd = __fadd_rn(__fadd_rn(__fmul_rn(dx,dx), __fmul_rn(dy,dy)), __fmul_rn(dz,dz));
      if (!(dd > k2df)) {                        // fast reject; == still takes insert (tie by sid)
        unsigned long long key = ((unsigned long long)__float_as_uint(dd) << 32)
                               | (unsigned long long)__float_as_uint(f4.w); // low = sid
        insK(key, k0, k1, k2);
        k2df = __uint_as_float((unsigned)(k2 >> 32));
      }
    }
    sk[v][j][0] = k0; sk[v][j][1] = k1; sk[v][j][2] = k2;
  }
  __syncthreads();

  // ---- phase 2b: merge 8x3 keys per voxel + emit (threads 0..26) ----
  if (tid < TV) {
    const int vv = tid;
    const float gx = qx + gsel(vv / 9);
    const float gy = qy + gsel((vv / 3) % 3);
    const float gz = qz + gsel(vv % 3);
    unsigned long long k0 = ~0ull, k1 = ~0ull, k2 = ~0ull;
    #pragma unroll
    for (int jj = 0; jj < 8; jj++) {
      insK(sk[vv][jj][0], k0, k1, k2);
      insK(sk[vv][jj][1], k0, k1, k2);
      insK(sk[vv][jj][2], k0, k1, k2);
    }
    const int base = m * TV + vv;
    if (cnt > 0) {
      unsigned long long ks[3] = {k0, k1, k2};
      float d[3]; int gi[3]; bool ok[3];
      #pragma unroll
      for (int r = 0; r < 3; r++) {
        unsigned db = (unsigned)(ks[r] >> 32);
        ok[r] = (db != 0xFFFFFFFFu);
        d[r]  = ok[r] ? __uint_as_float(db) : 1e10f;
        gi[r] = ok[r] ? (int)(unsigned)(ks[r] & 0xFFFFFFFFull) : 0;
      }
      float r0 = 1.0f / (d[0] + 1e-8f);
      float r1 = 1.0f / (d[1] + 1e-8f);
      float r2 = 1.0f / (d[2] + 1e-8f);
      float den = fmaxf(r0 + r1 + r2, 1e-8f);
      nnW[base*3+0] = r0 / den; nnW[base*3+1] = r1 / den; nnW[base*3+2] = r2 / den;
      nnGI[base*3+0] = gi[0]; nnGI[base*3+1] = gi[1]; nnGI[base*3+2] = gi[2];
      #pragma unroll
      for (int r = 0; r < 3; r++) {
        if (ok[r]) {
          nnLX[base*9 + r*3 + 0] = gx - sup_xyz[gi[r]*3 + 0];
          nnLX[base*9 + r*3 + 1] = gy - sup_xyz[gi[r]*3 + 1];
          nnLX[base*9 + r*3 + 2] = gz - sup_xyz[gi[r]*3 + 2];
        } else {
          nnLX[base*9 + r*3 + 0] = 0.0f;
          nnLX[base*9 + r*3 + 1] = 0.0f;
          nnLX[base*9 + r*3 + 2] = 0.0f;
        }
      }
    } else {
      #pragma unroll
      for (int r = 0; r < 3; r++) {
        nnW[base*3+r] = 0.0f; nnGI[base*3+r] = 0;
        nnLX[base*9+r*3+0] = 0.0f; nnLX[base*9+r*3+1] = 0.0f; nnLX[base*9+r*3+2] = 0.0f;
      }
    }
  }
}

// ---------------- Kernel A3: interp features + grouped conv1, 8 queries per block ----------------
__global__ __launch_bounds__(256) void kA3(const float* __restrict__ sup_feat,
                                           const float* __restrict__ nnW,
                                           const int*   __restrict__ nnGI,
                                           const float* __restrict__ nnLX,
                                           const float* __restrict__ w1T,
                                           float* __restrict__ y1)
{
  __shared__ float s_feats[8][TV][CIN];
  __shared__ float s_w[8][TV][3];
  __shared__ int   s_gi[8][TV][3];

  const int m0  = blockIdx.x * 8;
  const int tid = threadIdx.x;

  for (int t = tid; t < 8*TV*3; t += 256) {
    int q = t / (TV*3), rem = t % (TV*3);
    s_w[q][rem/3][rem%3]  = nnW[m0*TV*3 + t];
    s_gi[q][rem/3][rem%3] = nnGI[m0*TV*3 + t];
  }
  for (int t = tid; t < 8*TV*9; t += 256) {
    int q = t / (TV*9), rem = t % (TV*9);
    s_feats[q][rem/9][32 + rem%9] = nnLX[m0*TV*9 + t];
  }
  __syncthreads();

  for (int t = tid; t < 8*TV*32; t += 256) {
    const int q = t / (TV*32), rem = t % (TV*32);
    const int v = rem >> 5, ch = rem & 31;
    s_feats[q][v][ch] = s_w[q][v][0] * sup_feat[s_gi[q][v][0]*32 + ch]
                      + s_w[q][v][1] * sup_feat[s_gi[q][v][1]*32 + ch]
                      + s_w[q][v][2] * sup_feat[s_gi[q][v][2]*32 + ch];
  }
  __syncthreads();

  for (int t = tid; t < CH1; t += 256) {
    const int v = t >> 5;
    float acc[8];
    #pragma unroll
    for (int q = 0; q < 8; q++) acc[q] = 0.0f;
    for (int k = 0; k < CIN; k++) {
      float w = w1T[k * CH1 + t];
      #pragma unroll
      for (int q = 0; q < 8; q++) acc[q] += s_feats[q][v][k] * w;
    }
    #pragma unroll
    for (int q = 0; q < 8; q++) y1[(size_t)(m0 + q) * CH1 + t] = acc[q];
  }
}

// ---------------- Kernel B: BN1 stats ----------------
__global__ void kB(const float* __restrict__ y1, float* __restrict__ stats1)
{
  const int c  = threadIdx.x;        // 864 threads
  const int m0 = blockIdx.x * 64;    // 64 blocks
  float s = 0.0f, ss = 0.0f;
  for (int r = 0; r < 64; r++) {
    float v = y1[(size_t)(m0 + r) * CH1 + c];
    s += v; ss += v * v;
  }
  atomicAdd(&stats1[c],       s);
  atomicAdd(&stats1[CH1 + c], ss);
}

// ---------------- Kernel S: BN1 scale/shift precompute ----------------
__global__ void kS(const float* __restrict__ stats1,
                   const float* __restrict__ g1, const float* __restrict__ b1,
                   float* __restrict__ scsg, float* __restrict__ shsg)
{
  int c = blockIdx.x * 256 + threadIdx.x;
  if (c < CH1) {
    float s  = stats1[c], ssq = stats1[CH1 + c];
    float mu  = s  * (1.0f / M_Q);
    float var = ssq * (1.0f / M_Q) - mu * mu;
    float r   = 1.0f / sqrtf(var + 1e-5f);
    float gg = g1[c];
    scsg[c] = r * gg;
    shsg[c] = b1[c] - mu * r * gg;
  }
}

// ---------------- Kernel C: BN1-fused GEMM, 16x64 tile, 4 waves/block, 2x2/thread, grid 512 ----------------
__global__ __launch_bounds__(256) void kC(const float* __restrict__ y1,
                                          const float* __restrict__ scsg,
                                          const float* __restrict__ shsg,
                                          const float* __restrict__ w2T,
                                          float* __restrict__ z,
                                          float* __restrict__ stats2)   // [8][256]
{
  __shared__ float As[C2BK][21];      // [k][row], stride 21: conflict-free stores/reads
  __shared__ float Bs[C2BK][C2BN];    // 8 KB
  __shared__ float st_s[2][C2BN];

  const int tid = threadIdx.x;
  const int m0  = (blockIdx.x >> 1) * C2BM;
  const int bn0 = (blockIdx.x & 1) * C2BN;

  if (tid < 2*C2BN) st_s[tid >> 6][tid & 63] = 0.0f;

  // A staging: row = tid>>4 (0..15), k-pair = (tid&15)*2
  const int arow = tid >> 4;
  const int akp  = (tid & 15) * 2;
  // B staging: kk = tid>>3 (0..31), cols (tid&7)*8 .. +7
  const int bkk = tid >> 3;
  const int bc8 = (tid & 7) * 8;
  // compute: ty = tid>>5 (rows ty*2..+1), tx = tid&31 (cols tx*2..+1)
  const int ty = tid >> 5;
  const int tx = tid & 31;

  float2 pa  = *(const float2*)&y1[(size_t)(m0 + arow) * CH1 + akp];
  float2 psc = *(const float2*)&scsg[akp];
  float2 psh = *(const float2*)&shsg[akp];
  float4 pb0 = *(const float4*)&w2T[(size_t)bkk * CH2 + bn0 + bc8];
  float4 pb1 = *(const float4*)&w2T[(size_t)bkk * CH2 + bn0 + bc8 + 4];

  float a00 = 0.f, a01 = 0.f, a10 = 0.f, a11 = 0.f;

  for (int k0 = 0; k0 < CH1; k0 += C2BK) {
    __syncthreads();                       // previous tile fully consumed
    As[akp  ][arow] = fmaxf(pa.x * psc.x + psh.x, 0.0f);
    As[akp+1][arow] = fmaxf(pa.y * psc.y + psh.y, 0.0f);
    *(float4*)&Bs[bkk][bc8]     = pb0;
    *(float4*)&Bs[bkk][bc8 + 4] = pb1;
    __syncthreads();
    const int kn = k0 + C2BK;
    if (kn < CH1) {                        // prefetch next tile (overlaps compute)
      pa  = *(const float2*)&y1[(size_t)(m0 + arow) * CH1 + kn + akp];
      psc = *(const float2*)&scsg[kn + akp];
      psh = *(const float2*)&shsg[kn + akp];
      pb0 = *(const float4*)&w2T[(size_t)(kn + bkk) * CH2 + bn0 + bc8];
      pb1 = *(const float4*)&w2T[(size_t)(kn + bkk) * CH2 + bn0 + bc8 + 4];
    }
    #pragma unroll
    for (int kk = 0; kk < C2BK; kk++) {
      float2 av = *(const float2*)&As[kk][ty*2];
      float2 bv = *(const float2*)&Bs[kk][tx*2];
      a00 += av.x*bv.x; a01 += av.x*bv.y;
      a10 += av.y*bv.x; a11 += av.y*bv.y;
    }
  }

  *(float2*)&z[(size_t)(m0 + ty*2    ) * CH2 + bn0 + tx*2] = make_float2(a00, a01);
  *(float2*)&z[(size_t)(m0 + ty*2 + 1) * CH2 + bn0 + tx*2] = make_float2(a10, a11);

  atomicAdd(&st_s[0][tx*2    ], a00 + a10);
  atomicAdd(&st_s[0][tx*2 + 1], a01 + a11);
  atomicAdd(&st_s[1][tx*2    ], a00*a00 + a10*a10);
  atomicAdd(&st_s[1][tx*2 + 1], a01*a01 + a11*a11);
  __syncthreads();
  if (tid < 2*C2BN) {
    int which = tid >> 6, c = tid & 63;
    int copy = (blockIdx.x >> 1) & 7;      // spread contention over 8 copies
    atomicAdd(&stats2[copy*256 + which*128 + bn0 + c], st_s[which][c]);
  }
}

// ---------------- Kernel D: BN2 apply + ReLU -> f32 out ----------------
__global__ void kD(const float* __restrict__ z,
                   const float* __restrict__ stats2,   // [8][256]
                   const float* __restrict__ g2,
                   const float* __restrict__ b2,
                   float* __restrict__ out)
{
  int t = blockIdx.x * 256 + threadIdx.x;
  if (t >= M_Q * CH2) return;
  int c = t & 127;
  float s = 0.0f, ss = 0.0f;
  #pragma unroll
  for (int k = 0; k < 8; k++) {
    s  += stats2[k * 256 + c];
    ss += stats2[k * 256 + 128 + c];
  }
  float mu  = s  * (1.0f / M_Q);
  float var = ss * (1.0f / M_Q) - mu * mu;
  float r   = 1.0f / sqrtf(var + 1e-5f);
  float val = fmaxf((z[t] - mu) * r * g2[c] + b2[c], 0.0f);
  out[t] = val;
}

extern "C" void kernel_launch(void* const* d_in, const int* in_sizes, int n_in,
                              void* d_out, int out_size, void* d_ws, size_t ws_size,
                              hipStream_t stream)
{
  const float* sup_xyz  = (const float*)d_in[0];
  const float* sup_feat = (const float*)d_in[1];
  const float* new_xyz  = (const float*)d_in[2];
  const float* w1       = (const float*)d_in[3];
  const float* g1       = (const float*)d_in[4];
  const float* b1       = (const float*)d_in[5];
  const float* w2       = (const float*)d_in[6];
  const float* g2       = (const float*)d_in[7];
  const float* b2       = (const float*)d_in[8];
  float* out = (float*)d_out;

  char* ws = (char*)d_ws;
  float* y1     = (float*)(ws);                       // 14,155,776 B
  float* z      = (float*)(ws + 14155776);            //  2,097,152 B (aliased by w1T early)
  float* w2T    = (float*)(ws + 16252928);            //    442,368 B
  float* stats  = (float*)(ws + 16695296);            //     15,104 B (1728 + 2048 f32)
  int*   counts = (int*)  (ws + 16710400);            //        576 B
  int*   cursor = (int*)  (ws + 16710976);            //        576 B
  int*   starts = (int*)  (ws + 16711552);            //        580 B
  float* xs     = (float*)(ws + 16712132);            //     65,536 B
  float* ys     = (float*)(ws + 16777668);
  float* zs     = (float*)(ws + 16843204);
  int*   sid    = (int*)  (ws + 16908740);
  float* nnW    = (float*)(ws + 16974276);            //  1,327,104 B
  int*   nnGI   = (int*)  (ws + 18301380);            //  1,327,104 B
  float* nnLX   = (float*)(ws + 19628484);            //  3,981,312 B  (end 23,609,796)
  float* stats1 = stats;
  float* stats2 = stats + 2 * CH1;                    // 8 copies x 256
  // w1T (141,696 B) aliases z: kA3 (last reader) runs before kC (writer of z).
  float* w1T    = z;
  // scsg/shsg (3456 B each) alias xs/ys: dead after kA12; kS rewrites before kC reads.
  float* scsg   = xs;
  float* shsg   = ys;

  // zero stats + counts + cursor in one contiguous memset
  hipMemsetAsync(stats, 0, 15104 + 576 + 576, stream);

  const int WT_TOT = CIN*CH1 + CH1*CH2;
  hipLaunchKernelGGL(kWT,     dim3((WT_TOT + 255) / 256), dim3(256), 0, stream, w1, w1T, w2, w2T);
  hipLaunchKernelGGL(kCount,  dim3((N_SUP + 255) / 256),  dim3(256), 0, stream, sup_xyz, counts);
  hipLaunchKernelGGL(kScan,   dim3(1),                    dim3(256), 0, stream, counts, starts, cursor);
  hipLaunchKernelGGL(kScatter,dim3((N_SUP + 255) / 256),  dim3(256), 0, stream, sup_xyz, cursor, xs, ys, zs, sid);
  hipLaunchKernelGGL(kA12,    dim3(M_Q),                  dim3(256), 0, stream, xs, ys, zs, sid, starts, new_xyz, sup_xyz, nnW, nnGI, nnLX);
  hipLaunchKernelGGL(kA3,     dim3(M_Q / 8),              dim3(256), 0, stream, sup_feat, nnW, nnGI, nnLX, w1T, y1);
  hipLaunchKernelGGL(kB,      dim3(M_Q / 64),             dim3(CH1), 0, stream, y1, stats1);
  hipLaunchKernelGGL(kS,      dim3((CH1 + 255) / 256),    dim3(256), 0, stream, stats1, g1, b1, scsg, shsg);
  hipLaunchKernelGGL(kC,      dim3((M_Q / C2BM) * 2),     dim3(256), 0, stream, y1, scsg, shsg, w2T, z, stats2);
  hipLaunchKernelGGL(kD,      dim3((M_Q*CH2 + 255) / 256),dim3(256), 0, stream, z, stats2, g2, b2, out);
}